// Round 8
// baseline (675.883 us; speedup 1.0000x reference)
//
#include <hip/hip_runtime.h>

// MHA forward. f32 in/out; bf16 MFMA compute (16x16x32), fp32 accum.
// Pipeline: cvt_x + transposeW -> merged QKV GEMM -> flash attention
//           (barrier-free: 1 wave = 1 q-tile of 16 rows, K/V direct from
//           global via L1/L2) -> out GEMM.
// Workspace (u16): WqT,WkT,WvT (contig 3072x1024 Bt), WoT, xb/Ctx (alias),
// Q, K, Vt = 72 MB.
//
// R8 vs R7: attention restructured to ZERO block barriers. Each wave owns an
// independent 16-row q-tile; K/V fragments loaded straight from global (b128,
// same geometry as the LDS reads before); only wave-private P hop uses LDS
// (lgkmcnt + wave_barrier). Waves of a block share j-group (equal iters,
// shared K/V tiles in L1). R5-R7 showed the __syncthreads pair at ~6 resident
// waves/CU is the structural stall (occ 19%, Mfma 5%).

typedef unsigned short u16;
typedef __attribute__((ext_vector_type(8))) short short8;   // 8 bf16
typedef __attribute__((ext_vector_type(4))) float floatx4;  // 4 fp32

#define NEG_BIG (-1e30f)

__device__ __forceinline__ u16 f2bf(float f) {
  unsigned int u = __builtin_bit_cast(unsigned int, f);
  u += 0x7fffu + ((u >> 16) & 1u);
  return (u16)(u >> 16);
}

__device__ __forceinline__ short8 cvt8(const float* __restrict__ p) {
  const floatx4 a = *(const floatx4*)p;
  const floatx4 b = *(const floatx4*)(p + 4);
  short8 r;
  r[0] = (short)f2bf(a[0]); r[1] = (short)f2bf(a[1]);
  r[2] = (short)f2bf(a[2]); r[3] = (short)f2bf(a[3]);
  r[4] = (short)f2bf(b[0]); r[5] = (short)f2bf(b[1]);
  r[6] = (short)f2bf(b[2]); r[7] = (short)f2bf(b[3]);
  return r;
}

// async global->LDS, 16B/lane; LDS dest = wave-uniform base + lane*16 [m97]
__device__ __forceinline__ void gll16(const u16* g, u16* l) {
  __builtin_amdgcn_global_load_lds((const __attribute__((address_space(1))) void*)g,
                                   (__attribute__((address_space(3))) void*)l,
                                   16, 0, 0);
}

// ---------------------------------------------------------------------------
__global__ void cvt_x(const float* __restrict__ x, u16* __restrict__ xb) {
  const int i = blockIdx.x * 256 + threadIdx.x;  // 8 elems each
  *(short8*)(xb + (size_t)i * 8) = cvt8(x + (size_t)i * 8);
}

// ---------------------------------------------------------------------------
// 1024x1024 transpose + f32->bf16 (x4 matrices via grid.z).
__global__ void transpose4(const float* __restrict__ s0, const float* __restrict__ s1,
                           const float* __restrict__ s2, const float* __restrict__ s3,
                           u16* __restrict__ d0, u16* __restrict__ d1,
                           u16* __restrict__ d2, u16* __restrict__ d3) {
  __shared__ u16 tile[64][72];
  const float* src; u16* dst;
  switch (blockIdx.z) {
    case 0: src = s0; dst = d0; break;
    case 1: src = s1; dst = d1; break;
    case 2: src = s2; dst = d2; break;
    default: src = s3; dst = d3; break;
  }
  const int t = threadIdx.x;
  const int c = t & 63, rg = t >> 6;
  const int x0 = blockIdx.x * 64, y0 = blockIdx.y * 64;
#pragma unroll
  for (int i = 0; i < 16; ++i) {
    const int row = rg * 16 + i;
    tile[row][c] = f2bf(src[(size_t)(y0 + row) * 1024 + x0 + c]);
  }
  __syncthreads();
#pragma unroll
  for (int i = 0; i < 16; ++i) {
    const int row = rg * 16 + i;
    dst[(size_t)(x0 + row) * 1024 + y0 + c] = tile[c][row];
  }
}

// ---------------------------------------------------------------------------
// Merged QKV GEMM: A[8192,1024] bf16 @ Bt[3072,1024]^T (WqT|WkT|WvT) + bias.
// 128x128 tile, BK=32, m97 gll staging. Epilogue routes by segment.
__global__ __launch_bounds__(256, 2) void gemm_qkv(
    const u16* __restrict__ A, const u16* __restrict__ Bt,
    const float* __restrict__ bq, const float* __restrict__ bk,
    const float* __restrict__ bv,
    u16* __restrict__ Qb, u16* __restrict__ Kb, u16* __restrict__ Vtb) {
  const int K = 1024;
  __shared__ __align__(16) u16 As[128 * 32];
  __shared__ __align__(16) u16 Bs[128 * 32];
  const int t = threadIdx.x;
  const int w = t >> 6, l = t & 63;
  const int quad = l >> 4, l16 = l & 15;
  const int m0 = blockIdx.y * 128, n0 = blockIdx.x * 128;
  const int wr = w >> 1, wc = w & 1;

  floatx4 acc[4][4] = {};

  for (int k0 = 0; k0 < K; k0 += 32) {
    __syncthreads();
#pragma unroll
    for (int p = 0; p < 2; ++p) {
      const int c0 = (p * 4 + w) * 64;
      const int c = c0 + l;
      const int row = c >> 2;
      const int koff = (c & 3) * 8;
      gll16(A + (size_t)(m0 + row) * K + k0 + koff, &As[c0 * 8]);
      gll16(Bt + (size_t)(n0 + row) * K + k0 + koff, &Bs[c0 * 8]);
    }
    __syncthreads();

    short8 af[4], bf[4];
#pragma unroll
    for (int i = 0; i < 4; ++i)
      af[i] = *(const short8*)&As[(wr * 64 + i * 16 + l16) * 32 + quad * 8];
#pragma unroll
    for (int j = 0; j < 4; ++j)
      bf[j] = *(const short8*)&Bs[(wc * 64 + j * 16 + l16) * 32 + quad * 8];
#pragma unroll
    for (int i = 0; i < 4; ++i)
#pragma unroll
      for (int j = 0; j < 4; ++j)
        acc[i][j] = __builtin_amdgcn_mfma_f32_16x16x32_bf16(af[i], bf[j], acc[i][j], 0, 0, 0);
  }

  const int seg = n0 >> 10;  // 0=Q 1=K 2=V (128 | 1024 so block is seg-pure)
  const float* bias = (seg == 0) ? bq : (seg == 1) ? bk : bv;
#pragma unroll
  for (int j = 0; j < 4; ++j) {
    const int nn = (n0 & 1023) + wc * 64 + j * 16 + l16;
    const float bvs = bias[nn];
    const int h = nn >> 6, dh = nn & 63;
#pragma unroll
    for (int i = 0; i < 4; ++i) {
      const int rb = m0 + wr * 64 + i * 16 + quad * 4;
#pragma unroll
      for (int r = 0; r < 4; ++r) {
        const int m = rb + r;
        const float v = acc[i][j][r] + bvs;
        const int b = m >> 11, ll = m & 2047;
        if (seg < 2) {
          u16* dst = seg ? Kb : Qb;
          dst[((size_t)(b * 16 + h) * 2048 + ll) * 64 + dh] = f2bf(v);
        } else {
          Vtb[((size_t)(b * 16 + h) * 64 + dh) * 2048 + ll] = f2bf(v);
        }
      }
    }
  }
}

// ---------------------------------------------------------------------------
// Out GEMM: C[M,N] f32 = A[M,K] bf16 @ Bt[N,K]^T + bias[N].
__global__ __launch_bounds__(256, 2) void gemm_out(
    const u16* __restrict__ A, const u16* __restrict__ Bt,
    const float* __restrict__ bias, float* __restrict__ C, int M, int N, int K) {
  __shared__ __align__(16) u16 As[128 * 32];
  __shared__ __align__(16) u16 Bs[128 * 32];
  const int t = threadIdx.x;
  const int w = t >> 6, l = t & 63;
  const int quad = l >> 4, l16 = l & 15;
  const int m0 = blockIdx.y * 128, n0 = blockIdx.x * 128;
  const int wr = w >> 1, wc = w & 1;

  floatx4 acc[4][4] = {};

  for (int k0 = 0; k0 < K; k0 += 32) {
    __syncthreads();
#pragma unroll
    for (int p = 0; p < 2; ++p) {
      const int c0 = (p * 4 + w) * 64;
      const int c = c0 + l;
      const int row = c >> 2;
      const int koff = (c & 3) * 8;
      gll16(A + (size_t)(m0 + row) * K + k0 + koff, &As[c0 * 8]);
      gll16(Bt + (size_t)(n0 + row) * K + k0 + koff, &Bs[c0 * 8]);
    }
    __syncthreads();

    short8 af[4], bf[4];
#pragma unroll
    for (int i = 0; i < 4; ++i)
      af[i] = *(const short8*)&As[(wr * 64 + i * 16 + l16) * 32 + quad * 8];
#pragma unroll
    for (int j = 0; j < 4; ++j)
      bf[j] = *(const short8*)&Bs[(wc * 64 + j * 16 + l16) * 32 + quad * 8];
#pragma unroll
    for (int i = 0; i < 4; ++i)
#pragma unroll
      for (int j = 0; j < 4; ++j)
        acc[i][j] = __builtin_amdgcn_mfma_f32_16x16x32_bf16(af[i], bf[j], acc[i][j], 0, 0, 0);
  }

#pragma unroll
  for (int j = 0; j < 4; ++j) {
    const int n = n0 + wc * 64 + j * 16 + l16;
    const float bvs = bias[n];
#pragma unroll
    for (int i = 0; i < 4; ++i) {
      const int rb = m0 + wr * 64 + i * 16 + quad * 4;
#pragma unroll
      for (int r = 0; r < 4; ++r)
        C[(size_t)(rb + r) * N + n] = acc[i][j][r] + bvs;
    }
  }
}

// ---------------------------------------------------------------------------
// Flash attention, causal, BARRIER-FREE. One wave = one 16-row q-tile.
// Block x: bh = x>>5, j = 31-(x&31) (heavy first); wave w -> q-tile j*4+w
// (16 rows at q0=(j*4+w)*16), iterates j+1 k-tiles of 64 cols. All 4 waves
// share the K/V tiles (L1 locality) and have IDENTICAL iteration counts.
// K/V fragments read directly from global; only P hop uses wave-private LDS.
#define ATT_STRIDE 68
__global__ __launch_bounds__(256) void attn_kernel(
    const u16* __restrict__ Q, const u16* __restrict__ K,
    const u16* __restrict__ Vt, u16* __restrict__ ctx) {
  __shared__ __align__(16) u16 Ps[4 * 16 * ATT_STRIDE];  // per-wave P hop

  const int t = threadIdx.x;
  const int w = t >> 6, l = t & 63;
  const int quad = l >> 4, l16 = l & 15;
  const int bh = blockIdx.x >> 5;
  const int j = 31 - (blockIdx.x & 31);
  const int q0 = (j * 4 + w) * 16;
  const int nkt = j + 1;
  const size_t base = (size_t)bh * (2048 * 64);
  u16* Pw = &Ps[w * 16 * ATT_STRIDE];

  // Q fragments (A-layout): row = q0+l16, k = ks*32+quad*8
  short8 aq[2];
#pragma unroll
  for (int ks = 0; ks < 2; ++ks)
    aq[ks] = *(const short8*)(Q + base + (size_t)(q0 + l16) * 64 + ks * 32 + quad * 8);

  floatx4 o[4] = {};
  float mrow[4], lrow[4];
#pragma unroll
  for (int r = 0; r < 4; ++r) { mrow[r] = NEG_BIG; lrow[r] = 0.f; }

  for (int kt = 0; kt < nkt; ++kt) {
    const int k0 = kt * 64;

    // K B-fragments direct from global: row k0+tn*16+l16, k = ks*32+quad*8
    short8 bk[2][4];
#pragma unroll
    for (int ks = 0; ks < 2; ++ks)
#pragma unroll
      for (int tn = 0; tn < 4; ++tn)
        bk[ks][tn] = *(const short8*)(K + base +
            (size_t)(k0 + tn * 16 + l16) * 64 + ks * 32 + quad * 8);

    floatx4 s[4] = {};
#pragma unroll
    for (int ks = 0; ks < 2; ++ks)
#pragma unroll
      for (int tn = 0; tn < 4; ++tn)
        s[tn] = __builtin_amdgcn_mfma_f32_16x16x32_bf16(aq[ks], bk[ks][tn], s[tn], 0, 0, 0);

    // V^T B-fragments issued BEFORE softmax so their latency hides behind it.
    // row (dh) = td*16+l16, k (l) = k0+ks*32+quad*8
    short8 bv[2][4];
#pragma unroll
    for (int ks = 0; ks < 2; ++ks)
#pragma unroll
      for (int td = 0; td < 4; ++td)
        bv[ks][td] = *(const short8*)(Vt + base +
            (size_t)(td * 16 + l16) * 2048 + k0 + ks * 32 + quad * 8);

    // scale + causal mask (only last k-tile intersects the diagonal)
    const bool diag = (kt == nkt - 1);
#pragma unroll
    for (int tn = 0; tn < 4; ++tn)
#pragma unroll
      for (int r = 0; r < 4; ++r) {
        float v = s[tn][r] * 0.125f;  // 1/sqrt(64)
        if (diag && (tn * 16 + l16 > w * 16 + quad * 4 + r)) v = NEG_BIG;
        s[tn][r] = v;
      }

    // online softmax (row's 64 cols across one quad's 16 lanes)
    float alpha[4];
#pragma unroll
    for (int r = 0; r < 4; ++r) {
      float mx = fmaxf(fmaxf(s[0][r], s[1][r]), fmaxf(s[2][r], s[3][r]));
#pragma unroll
      for (int off = 8; off >= 1; off >>= 1)
        mx = fmaxf(mx, __shfl_xor(mx, off, 16));
      const float mnew = fmaxf(mrow[r], mx);
      alpha[r] = __expf(mrow[r] - mnew);
      mrow[r] = mnew;
      float rs = 0.f;
#pragma unroll
      for (int tn = 0; tn < 4; ++tn) {
        const float p = __expf(s[tn][r] - mnew);
        s[tn][r] = p;
        rs += p;
      }
#pragma unroll
      for (int off = 8; off >= 1; off >>= 1)
        rs += __shfl_xor(rs, off, 16);
      lrow[r] = lrow[r] * alpha[r] + rs;
    }
#pragma unroll
    for (int td = 0; td < 4; ++td)
#pragma unroll
      for (int r = 0; r < 4; ++r) o[td][r] *= alpha[r];

    // P: C-layout -> wave-private LDS -> A-layout (wave-level sync only)
#pragma unroll
    for (int tn = 0; tn < 4; ++tn)
#pragma unroll
      for (int r = 0; r < 4; ++r)
        Pw[(quad * 4 + r) * ATT_STRIDE + tn * 16 + l16] = f2bf(s[tn][r]);
    __asm__ volatile("s_waitcnt lgkmcnt(0)" ::: "memory");
    __builtin_amdgcn_wave_barrier();

    short8 ap[2];
#pragma unroll
    for (int ks = 0; ks < 2; ++ks)
      ap[ks] = *(const short8*)&Pw[l16 * ATT_STRIDE + ks * 32 + quad * 8];

    // O += P V : 8 MFMA
#pragma unroll
    for (int ks = 0; ks < 2; ++ks)
#pragma unroll
      for (int td = 0; td < 4; ++td)
        o[td] = __builtin_amdgcn_mfma_f32_16x16x32_bf16(ap[ks], bv[ks][td], o[td], 0, 0, 0);
  }

  // normalize + store ctx[b, l, h*64+dh] (bf16)
  const int b = bh >> 4, h = bh & 15;
#pragma unroll
  for (int r = 0; r < 4; ++r) {
    const float inv = 1.f / lrow[r];
    const int gq = q0 + quad * 4 + r;
    const size_t rowbase = ((size_t)(b * 2048 + gq)) * 1024 + h * 64;
#pragma unroll
    for (int td = 0; td < 4; ++td)
      ctx[rowbase + td * 16 + l16] = f2bf(o[td][r] * inv);
  }
}

// ---------------------------------------------------------------------------
extern "C" void kernel_launch(void* const* d_in, const int* in_sizes, int n_in,
                              void* d_out, int out_size, void* d_ws, size_t ws_size,
                              hipStream_t stream) {
  const float* x  = (const float*)d_in[0];
  // d_in[1] = attn_mask (causal tril) — implemented analytically
  const float* Wq = (const float*)d_in[2];
  const float* bq = (const float*)d_in[3];
  const float* Wk = (const float*)d_in[4];
  const float* bk = (const float*)d_in[5];
  const float* Wv = (const float*)d_in[6];
  const float* bv = (const float*)d_in[7];
  const float* Wo = (const float*)d_in[8];
  const float* bo = (const float*)d_in[9];

  u16* ws = (u16*)d_ws;
  const size_t WSZ = 1u << 20;   // 1024*1024
  const size_t TSZ = 8u << 20;   // 8192*1024
  u16* WqT = ws;                 // WqT|WkT|WvT contiguous = 3072x1024 Bt
  u16* WkT = ws + WSZ;
  u16* WvT = ws + 2 * WSZ;
  u16* WoT = ws + 3 * WSZ;
  u16* xb  = ws + 4 * WSZ;       // x as bf16; reused as Ctx after attention
  u16* Qb  = xb + TSZ;
  u16* Kb  = Qb + TSZ;
  u16* Vtb = Kb + TSZ;
  u16* Ctx = xb;

  const dim3 tb(256);
  cvt_x<<<dim3(4096), tb, 0, stream>>>(x, xb);
  transpose4<<<dim3(16, 16, 4), tb, 0, stream>>>(Wq, Wk, Wv, Wo, WqT, WkT, WvT, WoT);
  gemm_qkv<<<dim3(24, 64), tb, 0, stream>>>(xb, WqT, bq, bk, bv, Qb, Kb, Vtb);
  attn_kernel<<<dim3(2048), tb, 0, stream>>>(Qb, Kb, Vtb, Ctx);
  gemm_out<<<dim3(8, 64), tb, 0, stream>>>(Ctx, WoT, bo, (float*)d_out, 8192, 1024, 1024);
}

// Round 9
// 418.190 us; speedup vs baseline: 1.6162x; 1.6162x over previous
//
#include <hip/hip_runtime.h>

// MHA forward. f32 in/out; bf16 MFMA compute (16x16x32), fp32 accum.
// Pipeline: cvt_x + transposeW -> merged QKV GEMM (all coalesced writes)
//           -> transpose_v -> flash attention (DPP softmax, dbuf gll16 K/V,
//           1 barrier/iter) -> out GEMM.
// Workspace (u16): WqT,WkT,WvT(contig Bt),WoT (1M ea), xb(8M; ->Vtb),
// Qb, Kb, Vb(8M; ->Ctx) = 72 MB.
//
// R9 vs R8: (1) softmax reductions via DPP butterflies (VALU pipe) instead of
// __shfl_xor (ds_bpermute, ~100cyc each serial — the real chain). (2) K/V via
// double-buffered global_load_lds w/ chunk-XOR swizzle, 1 __syncthreads/iter.
// (3) V written coalesced + separate LDS transpose pass (R8's mode-2 epilogue
// scattered 2B writes at 4KB stride).

typedef unsigned short u16;
typedef __attribute__((ext_vector_type(8))) short short8;   // 8 bf16
typedef __attribute__((ext_vector_type(4))) float floatx4;  // 4 fp32

#define NEG_BIG (-1e30f)

__device__ __forceinline__ u16 f2bf(float f) {
  unsigned int u = __builtin_bit_cast(unsigned int, f);
  u += 0x7fffu + ((u >> 16) & 1u);
  return (u16)(u >> 16);
}

__device__ __forceinline__ short8 cvt8(const float* __restrict__ p) {
  const floatx4 a = *(const floatx4*)p;
  const floatx4 b = *(const floatx4*)(p + 4);
  short8 r;
  r[0] = (short)f2bf(a[0]); r[1] = (short)f2bf(a[1]);
  r[2] = (short)f2bf(a[2]); r[3] = (short)f2bf(a[3]);
  r[4] = (short)f2bf(b[0]); r[5] = (short)f2bf(b[1]);
  r[6] = (short)f2bf(b[2]); r[7] = (short)f2bf(b[3]);
  return r;
}

// async global->LDS, 16B/lane; LDS dest = wave-uniform base + lane*16 [m97]
__device__ __forceinline__ void gll16(const u16* g, u16* l) {
  __builtin_amdgcn_global_load_lds((const __attribute__((address_space(1))) void*)g,
                                   (__attribute__((address_space(3))) void*)l,
                                   16, 0, 0);
}

// DPP cross-lane (VALU pipe). 16-lane butterfly reduction:
// xor1 = quad_perm(1,0,3,2)=0xB1, xor2 = quad_perm(2,3,0,1)=0x4E,
// then row_half_mirror(0x141) [quads uniform -> swaps quad pairs],
// then row_mirror(0x140) [8-halves uniform -> swaps halves].
template <int CTRL>
__device__ __forceinline__ float dpp_f(float x) {
  const int xi = __builtin_bit_cast(int, x);
  return __builtin_bit_cast(float,
      __builtin_amdgcn_update_dpp(xi, xi, CTRL, 0xF, 0xF, false));
}
__device__ __forceinline__ float rmax16(float x) {
  x = fmaxf(x, dpp_f<0xB1>(x));
  x = fmaxf(x, dpp_f<0x4E>(x));
  x = fmaxf(x, dpp_f<0x141>(x));
  x = fmaxf(x, dpp_f<0x140>(x));
  return x;
}
__device__ __forceinline__ float rsum16(float x) {
  x += dpp_f<0xB1>(x);
  x += dpp_f<0x4E>(x);
  x += dpp_f<0x141>(x);
  x += dpp_f<0x140>(x);
  return x;
}

// ---------------------------------------------------------------------------
__global__ void cvt_x(const float* __restrict__ x, u16* __restrict__ xb) {
  const int i = blockIdx.x * 256 + threadIdx.x;  // 8 elems each
  *(short8*)(xb + (size_t)i * 8) = cvt8(x + (size_t)i * 8);
}

// ---------------------------------------------------------------------------
// 1024x1024 transpose + f32->bf16 (x4 matrices via grid.z).
__global__ void transpose4(const float* __restrict__ s0, const float* __restrict__ s1,
                           const float* __restrict__ s2, const float* __restrict__ s3,
                           u16* __restrict__ d0, u16* __restrict__ d1,
                           u16* __restrict__ d2, u16* __restrict__ d3) {
  __shared__ u16 tile[64][72];
  const float* src; u16* dst;
  switch (blockIdx.z) {
    case 0: src = s0; dst = d0; break;
    case 1: src = s1; dst = d1; break;
    case 2: src = s2; dst = d2; break;
    default: src = s3; dst = d3; break;
  }
  const int t = threadIdx.x;
  const int c = t & 63, rg = t >> 6;
  const int x0 = blockIdx.x * 64, y0 = blockIdx.y * 64;
#pragma unroll
  for (int i = 0; i < 16; ++i) {
    const int row = rg * 16 + i;
    tile[row][c] = f2bf(src[(size_t)(y0 + row) * 1024 + x0 + c]);
  }
  __syncthreads();
#pragma unroll
  for (int i = 0; i < 16; ++i) {
    const int row = rg * 16 + i;
    dst[(size_t)(x0 + row) * 1024 + y0 + c] = tile[c][row];
  }
}

// ---------------------------------------------------------------------------
// Per-head V transpose: Vb [b,h,l,dh] -> Vt [b,h,dh,l]. Coalesced both sides.
__global__ void transpose_v(const u16* __restrict__ Vb, u16* __restrict__ Vt) {
  __shared__ u16 tile[64][66];  // stride 66: column reads 2-way only
  const int bh = blockIdx.y;
  const int l0 = blockIdx.x * 64;
  const size_t base = (size_t)bh * (2048 * 64);
  const int t = threadIdx.x;
#pragma unroll
  for (int c = t; c < 512; c += 256) {
    const int row = c >> 3, cc = c & 7;
    *(short8*)&tile[row][cc * 8] =
        *(const short8*)(Vb + base + (size_t)(l0 + row) * 64 + cc * 8);
  }
  __syncthreads();
  const int c2 = t & 63, rg = t >> 6;
#pragma unroll
  for (int i = 0; i < 16; ++i) {
    const int dr = rg * 16 + i;
    Vt[base + (size_t)dr * 2048 + l0 + c2] = tile[c2][dr];
  }
}

// ---------------------------------------------------------------------------
// Merged QKV GEMM: A[8192,1024] bf16 @ Bt[3072,1024]^T (WqT|WkT|WvT) + bias.
// 128x128 tile, BK=32, m97 gll staging. All segs write [b,h,l,dh] (coalesced).
__global__ __launch_bounds__(256, 2) void gemm_qkv(
    const u16* __restrict__ A, const u16* __restrict__ Bt,
    const float* __restrict__ bq, const float* __restrict__ bk,
    const float* __restrict__ bv,
    u16* __restrict__ Qb, u16* __restrict__ Kb, u16* __restrict__ Vb) {
  const int K = 1024;
  __shared__ __align__(16) u16 As[128 * 32];
  __shared__ __align__(16) u16 Bs[128 * 32];
  const int t = threadIdx.x;
  const int w = t >> 6, l = t & 63;
  const int quad = l >> 4, l16 = l & 15;
  const int m0 = blockIdx.y * 128, n0 = blockIdx.x * 128;
  const int wr = w >> 1, wc = w & 1;

  floatx4 acc[4][4] = {};

  for (int k0 = 0; k0 < K; k0 += 32) {
    __syncthreads();
#pragma unroll
    for (int p = 0; p < 2; ++p) {
      const int c0 = (p * 4 + w) * 64;
      const int c = c0 + l;
      const int row = c >> 2;
      const int koff = (c & 3) * 8;
      gll16(A + (size_t)(m0 + row) * K + k0 + koff, &As[c0 * 8]);
      gll16(Bt + (size_t)(n0 + row) * K + k0 + koff, &Bs[c0 * 8]);
    }
    __syncthreads();

    short8 af[4], bf[4];
#pragma unroll
    for (int i = 0; i < 4; ++i)
      af[i] = *(const short8*)&As[(wr * 64 + i * 16 + l16) * 32 + quad * 8];
#pragma unroll
    for (int j = 0; j < 4; ++j)
      bf[j] = *(const short8*)&Bs[(wc * 64 + j * 16 + l16) * 32 + quad * 8];
#pragma unroll
    for (int i = 0; i < 4; ++i)
#pragma unroll
      for (int j = 0; j < 4; ++j)
        acc[i][j] = __builtin_amdgcn_mfma_f32_16x16x32_bf16(af[i], bf[j], acc[i][j], 0, 0, 0);
  }

  const int seg = n0 >> 10;  // 0=Q 1=K 2=V
  const float* bias = (seg == 0) ? bq : (seg == 1) ? bk : bv;
  u16* dst = (seg == 0) ? Qb : (seg == 1) ? Kb : Vb;
#pragma unroll
  for (int j = 0; j < 4; ++j) {
    const int nn = (n0 & 1023) + wc * 64 + j * 16 + l16;
    const float bvs = bias[nn];
    const int h = nn >> 6, dh = nn & 63;
#pragma unroll
    for (int i = 0; i < 4; ++i) {
      const int rb = m0 + wr * 64 + i * 16 + quad * 4;
#pragma unroll
      for (int r = 0; r < 4; ++r) {
        const int m = rb + r;
        const int b = m >> 11, ll = m & 2047;
        dst[((size_t)(b * 16 + h) * 2048 + ll) * 64 + dh] = f2bf(acc[i][j][r] + bvs);
      }
    }
  }
}

// ---------------------------------------------------------------------------
// Out GEMM: C[M,N] f32 = A[M,K] bf16 @ Bt[N,K]^T + bias[N].
__global__ __launch_bounds__(256, 2) void gemm_out(
    const u16* __restrict__ A, const u16* __restrict__ Bt,
    const float* __restrict__ bias, float* __restrict__ C, int M, int N, int K) {
  __shared__ __align__(16) u16 As[128 * 32];
  __shared__ __align__(16) u16 Bs[128 * 32];
  const int t = threadIdx.x;
  const int w = t >> 6, l = t & 63;
  const int quad = l >> 4, l16 = l & 15;
  const int m0 = blockIdx.y * 128, n0 = blockIdx.x * 128;
  const int wr = w >> 1, wc = w & 1;

  floatx4 acc[4][4] = {};

  for (int k0 = 0; k0 < K; k0 += 32) {
    __syncthreads();
#pragma unroll
    for (int p = 0; p < 2; ++p) {
      const int c0 = (p * 4 + w) * 64;
      const int c = c0 + l;
      const int row = c >> 2;
      const int koff = (c & 3) * 8;
      gll16(A + (size_t)(m0 + row) * K + k0 + koff, &As[c0 * 8]);
      gll16(Bt + (size_t)(n0 + row) * K + k0 + koff, &Bs[c0 * 8]);
    }
    __syncthreads();

    short8 af[4], bf[4];
#pragma unroll
    for (int i = 0; i < 4; ++i)
      af[i] = *(const short8*)&As[(wr * 64 + i * 16 + l16) * 32 + quad * 8];
#pragma unroll
    for (int j = 0; j < 4; ++j)
      bf[j] = *(const short8*)&Bs[(wc * 64 + j * 16 + l16) * 32 + quad * 8];
#pragma unroll
    for (int i = 0; i < 4; ++i)
#pragma unroll
      for (int j = 0; j < 4; ++j)
        acc[i][j] = __builtin_amdgcn_mfma_f32_16x16x32_bf16(af[i], bf[j], acc[i][j], 0, 0, 0);
  }

#pragma unroll
  for (int j = 0; j < 4; ++j) {
    const int n = n0 + wc * 64 + j * 16 + l16;
    const float bvs = bias[n];
#pragma unroll
    for (int i = 0; i < 4; ++i) {
      const int rb = m0 + wr * 64 + i * 16 + quad * 4;
#pragma unroll
      for (int r = 0; r < 4; ++r)
        C[(size_t)(rb + r) * N + n] = acc[i][j][r] + bvs;
    }
  }
}

// ---------------------------------------------------------------------------
// Flash attention, causal. Block = (qt, bh); 4 waves x 16 q-rows, Q in regs.
// K/V 64x64 tiles double-buffered in LDS via gll16 with chunk-XOR swizzle
// (stride 64, conflict-free b128 reads). ONE __syncthreads per k-tile.
// Softmax reductions via DPP (VALU pipe). P hop wave-private (stride 68).
#define P_STRIDE 68
__global__ __launch_bounds__(256) void attn_kernel(
    const u16* __restrict__ Q, const u16* __restrict__ K,
    const u16* __restrict__ Vt, u16* __restrict__ ctx) {
  __shared__ __align__(16) u16 Ks[2][64 * 64];
  __shared__ __align__(16) u16 Vs[2][64 * 64];
  __shared__ __align__(16) u16 Ps[4 * 16 * P_STRIDE];

  const int t = threadIdx.x;
  const int w = t >> 6, l = t & 63;
  const int quad = l >> 4, l16 = l & 15;
  const int qt = gridDim.x - 1 - blockIdx.x;  // heavy tiles first
  const int bh = blockIdx.y;
  const int q0 = qt * 64;
  const int nkt = qt + 1;
  const size_t base = (size_t)bh * (2048 * 64);
  u16* Pw = &Ps[w * 16 * P_STRIDE];

  // staging geometry: phys chunk pc = (p*4+w)*64 + l; logical row r = pc>>3,
  // chunk cl = (pc&7) ^ (r&7). gll16 dest = chunk-contiguous (lane*16).
  const int pc0 = w * 64 + l, pc1 = (4 + w) * 64 + l;
  const int sr0 = pc0 >> 3, sc0 = (pc0 & 7) ^ (sr0 & 7);
  const int sr1 = pc1 >> 3, sc1 = (pc1 & 7) ^ (sr1 & 7);

  // Q fragments (A-layout): row = q0+w*16+l16, k = ks*32+quad*8
  short8 aq[2];
#pragma unroll
  for (int ks = 0; ks < 2; ++ks)
    aq[ks] = *(const short8*)(Q + base + (size_t)(q0 + w * 16 + l16) * 64 + ks * 32 + quad * 8);

  // prefetch tile 0 into buf 0
  {
    u16* kb = &Ks[0][(w * 64) * 8];   // wave-uniform base (chunk p=0 slot)
    u16* kb1 = &Ks[0][((4 + w) * 64) * 8];
    gll16(K + base + (size_t)sr0 * 64 + sc0 * 8, kb);
    gll16(K + base + (size_t)sr1 * 64 + sc1 * 8, kb1);
    u16* vb = &Vs[0][(w * 64) * 8];
    u16* vb1 = &Vs[0][((4 + w) * 64) * 8];
    gll16(Vt + base + (size_t)sr0 * 2048 + sc0 * 8, vb);
    gll16(Vt + base + (size_t)sr1 * 2048 + sc1 * 8, vb1);
  }

  floatx4 o[4] = {};
  float mrow[4], lrow[4];
#pragma unroll
  for (int r = 0; r < 4; ++r) { mrow[r] = NEG_BIG; lrow[r] = 0.f; }

  const int swz = (l16 & 7);  // fragment-read chunk swizzle

  for (int kt = 0; kt < nkt; ++kt) {
    const int cur = kt & 1, nxt = cur ^ 1;
    __syncthreads();  // drains gll16s for buf[cur]; protects buf[nxt] reads
    if (kt + 1 < nkt) {
      const int kn = (kt + 1) * 64;
      gll16(K + base + (size_t)(kn + sr0) * 64 + sc0 * 8, &Ks[nxt][(w * 64) * 8]);
      gll16(K + base + (size_t)(kn + sr1) * 64 + sc1 * 8, &Ks[nxt][((4 + w) * 64) * 8]);
      gll16(Vt + base + (size_t)sr0 * 2048 + kn + sc0 * 8, &Vs[nxt][(w * 64) * 8]);
      gll16(Vt + base + (size_t)sr1 * 2048 + kn + sc1 * 8, &Vs[nxt][((4 + w) * 64) * 8]);
    }

    // S = Q K^T : 8 MFMA; K frag row tn*16+l16, chunk (ks*4+quad)^swz
    floatx4 s[4] = {};
#pragma unroll
    for (int ks = 0; ks < 2; ++ks)
#pragma unroll
      for (int tn = 0; tn < 4; ++tn) {
        const short8 bk = *(const short8*)&Ks[cur][(tn * 16 + l16) * 64 + (((ks * 4 + quad) ^ swz) << 3)];
        s[tn] = __builtin_amdgcn_mfma_f32_16x16x32_bf16(aq[ks], bk, s[tn], 0, 0, 0);
      }

    // scale + causal mask (only diagonal tile)
    const bool diag = (kt == nkt - 1);
#pragma unroll
    for (int tn = 0; tn < 4; ++tn)
#pragma unroll
      for (int r = 0; r < 4; ++r) {
        float v = s[tn][r] * 0.125f;  // 1/sqrt(64)
        if (diag && (tn * 16 + l16 > w * 16 + quad * 4 + r)) v = NEG_BIG;
        s[tn][r] = v;
      }

    // online softmax — DPP butterflies (row = 16-lane group = DPP row)
    float alpha[4];
#pragma unroll
    for (int r = 0; r < 4; ++r) {
      float mx = rmax16(fmaxf(fmaxf(s[0][r], s[1][r]), fmaxf(s[2][r], s[3][r])));
      const float mnew = fmaxf(mrow[r], mx);
      alpha[r] = __expf(mrow[r] - mnew);
      mrow[r] = mnew;
      float rs = 0.f;
#pragma unroll
      for (int tn = 0; tn < 4; ++tn) {
        const float p = __expf(s[tn][r] - mnew);
        s[tn][r] = p;
        rs += p;
      }
      lrow[r] = lrow[r] * alpha[r] + rsum16(rs);
    }
#pragma unroll
    for (int td = 0; td < 4; ++td)
#pragma unroll
      for (int r = 0; r < 4; ++r) o[td][r] *= alpha[r];

    // P: C-layout -> wave-private LDS -> A-layout
#pragma unroll
    for (int tn = 0; tn < 4; ++tn)
#pragma unroll
      for (int r = 0; r < 4; ++r)
        Pw[(quad * 4 + r) * P_STRIDE + tn * 16 + l16] = f2bf(s[tn][r]);
    __asm__ volatile("s_waitcnt lgkmcnt(0)" ::: "memory");
    __builtin_amdgcn_wave_barrier();

    short8 ap[2];
#pragma unroll
    for (int ks = 0; ks < 2; ++ks)
      ap[ks] = *(const short8*)&Pw[l16 * P_STRIDE + ks * 32 + quad * 8];

    // O += P V : 8 MFMA; V^T frag row td*16+l16 (=dh), chunk (ks*4+quad)^swz
#pragma unroll
    for (int ks = 0; ks < 2; ++ks)
#pragma unroll
      for (int td = 0; td < 4; ++td) {
        const short8 bv = *(const short8*)&Vs[cur][(td * 16 + l16) * 64 + (((ks * 4 + quad) ^ swz) << 3)];
        o[td] = __builtin_amdgcn_mfma_f32_16x16x32_bf16(ap[ks], bv, o[td], 0, 0, 0);
      }
  }

  // normalize + store ctx[b, l, h*64+dh] (bf16)
  const int b = bh >> 4, h = bh & 15;
#pragma unroll
  for (int r = 0; r < 4; ++r) {
    const float inv = 1.f / lrow[r];
    const int gq = q0 + w * 16 + quad * 4 + r;
    const size_t rowbase = ((size_t)(b * 2048 + gq)) * 1024 + h * 64;
#pragma unroll
    for (int td = 0; td < 4; ++td)
      ctx[rowbase + td * 16 + l16] = f2bf(o[td][r] * inv);
  }
}

// ---------------------------------------------------------------------------
extern "C" void kernel_launch(void* const* d_in, const int* in_sizes, int n_in,
                              void* d_out, int out_size, void* d_ws, size_t ws_size,
                              hipStream_t stream) {
  const float* x  = (const float*)d_in[0];
  // d_in[1] = attn_mask (causal tril) — implemented analytically
  const float* Wq = (const float*)d_in[2];
  const float* bq = (const float*)d_in[3];
  const float* Wk = (const float*)d_in[4];
  const float* bk = (const float*)d_in[5];
  const float* Wv = (const float*)d_in[6];
  const float* bv = (const float*)d_in[7];
  const float* Wo = (const float*)d_in[8];
  const float* bo = (const float*)d_in[9];

  u16* ws = (u16*)d_ws;
  const size_t WSZ = 1u << 20;   // 1024*1024
  const size_t TSZ = 8u << 20;   // 8192*1024
  u16* WqT = ws;                 // WqT|WkT|WvT contiguous = 3072x1024 Bt
  u16* WkT = ws + WSZ;
  u16* WvT = ws + 2 * WSZ;
  u16* WoT = ws + 3 * WSZ;
  u16* xb  = ws + 4 * WSZ;       // x bf16; dead after gemm_qkv -> reused as Vtb
  u16* Qb  = xb + TSZ;
  u16* Kb  = Qb + TSZ;
  u16* Vb  = Kb + TSZ;           // V [b,h,l,dh]; dead after transpose_v -> Ctx
  u16* Vtb = xb;
  u16* Ctx = Vb;

  const dim3 tb(256);
  cvt_x<<<dim3(4096), tb, 0, stream>>>(x, xb);
  transpose4<<<dim3(16, 16, 4), tb, 0, stream>>>(Wq, Wk, Wv, Wo, WqT, WkT, WvT, WoT);
  gemm_qkv<<<dim3(24, 64), tb, 0, stream>>>(xb, WqT, bq, bk, bv, Qb, Kb, Vb);
  transpose_v<<<dim3(32, 64), tb, 0, stream>>>(Vb, Vtb);
  attn_kernel<<<dim3(32, 64), tb, 0, stream>>>(Qb, Kb, Vtb, Ctx);
  gemm_out<<<dim3(8, 64), tb, 0, stream>>>(Ctx, WoT, bo, (float*)d_out, 8192, 1024, 1024);
}